// Round 14
// baseline (61.636 us; speedup 1.0000x reference)
//
#include <hip/hip_runtime.h>
#include <hip/hip_bf16.h>

// proto_net_loss, 3 dispatches (prep eliminated — each consumer converts weights
// into its own LDS; X read directly as f32 in fragment order):
//  gemm1: W1->LDS packed per block; H(packed bf16) = X @ W1 + BN partial stats
//  gemm2: W2->LDS packed per block; [BN finalize in head]
//         Z(packed bf16) = relu(H*sc+sh) @ W2 + f32 row norms
//  dist:  D = n1[i]+n2[j]-2*Z1@Z2^T; packed Z loads, float4 stores, XCD swizzle
//
// LDS packed weight layout (bf16): slot16B(ft,lq,l15) at byte ft*1024+lq*256+l15*16
// holds W[k][n] for k = t*32+lq*8+j (j=0..7), n = f*16+l15, ft = f*16+t.
// Bank check: lane-varying term lq*256+l15*16 -> 8 distinct 16B slots per 128B
// (2 lanes/slot = free 2-way) for both ds_write_b128 and ds_read_b128.

#define LAT 512
#define HID 128
#define EPSV 1e-5f
#define G1_LDS (131072 + 16640)  // W1 packed 128KB + union{T 64x65 f32 | sS/sQ 16KB}

typedef __attribute__((ext_vector_type(8))) short bf16x8;
typedef __attribute__((ext_vector_type(4))) float f32x4;

__device__ __forceinline__ unsigned short f2bf(float x) {  // RTNE
  unsigned int u = __builtin_bit_cast(unsigned int, x);
  return (unsigned short)((u + 0x7fffu + ((u >> 16) & 1u)) >> 16);
}
__device__ __forceinline__ float bf2f(unsigned short h) {
  unsigned int u = ((unsigned int)h) << 16;
  return __builtin_bit_cast(float, u);
}
// global packed store offset for acc[f][0..3] by lane (l15,lq) (round-13 verified)
__device__ __forceinline__ size_t pack4_off(int strip, int f, int l15, int lq) {
  return (size_t)strip * 2048 + (size_t)(f >> 1) * 512 + (size_t)l15 * 32 +
         (size_t)(((f & 1) * 2 + (lq >> 1)) * 8 + (lq & 1) * 4);
}

// convert one 64x64 f32 tile of W (row-major [K][128]) into packed LDS
// WL slot(f*TPF + tt, lq, l15); TPF = K/32 slots-per-frag (16 for W1, 4 for W2).
template <int TPF>
__device__ __forceinline__ void conv_tile(const float* __restrict__ W, int k0, int n0,
                                          float (*T)[65], unsigned short* WL, int tid) {
  {
    const int rr = tid >> 4, cc = (tid & 15) * 4;
#pragma unroll
    for (int i = 0; i < 4; ++i) {
      const int r = rr + i * 16;
      const float4 v = *(const float4*)(W + (size_t)(k0 + r) * HID + n0 + cc);
      T[cc + 0][r] = v.x; T[cc + 1][r] = v.y; T[cc + 2][r] = v.z; T[cc + 3][r] = v.w;
    }
  }
  __syncthreads();
  {
    const int nn = tid >> 2, q = (tid & 3) * 16;
    const int n = n0 + nn, f = n >> 4, nl = n & 15;
#pragma unroll
    for (int e8 = 0; e8 < 2; ++e8) {
      const int k = k0 + q + e8 * 8;
      const int tt = k >> 5, kq = (k >> 3) & 3;
      const int kl = q + e8 * 8;
      ushort4 lo = {f2bf(T[nn][kl + 0]), f2bf(T[nn][kl + 1]),
                    f2bf(T[nn][kl + 2]), f2bf(T[nn][kl + 3])};
      ushort4 hi = {f2bf(T[nn][kl + 4]), f2bf(T[nn][kl + 5]),
                    f2bf(T[nn][kl + 6]), f2bf(T[nn][kl + 7])};
      char* dst = (char*)WL + (size_t)(f * TPF + tt) * 1024 + kq * 256 + nl * 16;
      *(ushort4*)dst = lo;
      *(ushort4*)(dst + 8) = hi;
    }
  }
  __syncthreads();
}

// ---------------- gemm1: W1->LDS, H(packed) = X @ W1 + partial stats ----------------
extern __shared__ char smem_g1[];
__global__ __launch_bounds__(256) void k_gemm1(
    const float* __restrict__ X1, const float* __restrict__ X2, int nx,
    const float* __restrict__ W1, unsigned short* __restrict__ H,
    float* __restrict__ pS, float* __restrict__ pQ) {
  unsigned short* WL = (unsigned short*)smem_g1;            // 128KB packed W1
  char* aux = smem_g1 + 131072;
  float(*T)[65] = (float(*)[65])aux;                        // prologue staging
  float(*sS)[HID] = (float(*)[HID])aux;                     // epilogue stats (union)
  float(*sQ)[HID] = (float(*)[HID])(aux + 8192);
  const int tid = threadIdx.x, wid = tid >> 6, lane = tid & 63;
  const int l15 = lane & 15, lq = lane >> 4;

  // prologue: full W1 (512x128 f32, L2-hot) -> packed LDS
#pragma unroll 1
  for (int bi = 0; bi < 16; ++bi)
    conv_tile<16>(W1, (bi >> 1) * 64, (bi & 1) * 64, T, WL, tid);

  // main: wave = 16 rows x 128 cols, K=512; X read f32 in fragment order
  const int browBase = (int)blockIdx.x * 64;
  const int row0 = browBase + wid * 16;
  const float* X = (browBase < nx) ? X1 : X2;
  const int xrow = (browBase < nx) ? row0 : row0 - nx;
  const float* xptr = X + (size_t)(xrow + l15) * LAT + lq * 8;
  const char* wl = (const char*)WL + lq * 256 + l15 * 16;
  f32x4 acc[8];
#pragma unroll
  for (int f = 0; f < 8; ++f) acc[f] = (f32x4){0.f, 0.f, 0.f, 0.f};
#pragma unroll
  for (int t = 0; t < 16; ++t) {
    const float4 x0 = *(const float4*)(xptr + t * 32);
    const float4 x1 = *(const float4*)(xptr + t * 32 + 4);
    const float vv[8] = {x0.x, x0.y, x0.z, x0.w, x1.x, x1.y, x1.z, x1.w};
    bf16x8 xv;
#pragma unroll
    for (int i = 0; i < 8; ++i) xv[i] = (short)f2bf(vv[i]);
#pragma unroll
    for (int f = 0; f < 8; ++f) {
      const bf16x8 afr = *(const bf16x8*)(wl + (size_t)(f * 16 + t) * 1024);
      acc[f] = __builtin_amdgcn_mfma_f32_16x16x32_bf16(afr, xv, acc[f], 0, 0, 0);
    }
  }
  // store H fragment-packed
  const int strip = row0 >> 4;
#pragma unroll
  for (int f = 0; f < 8; ++f) {
    ushort4 hz = {f2bf(acc[f][0]), f2bf(acc[f][1]), f2bf(acc[f][2]), f2bf(acc[f][3])};
    *(ushort4*)(H + pack4_off(strip, f, l15, lq)) = hz;
  }
  // partial stats (aux region now free of T use)
#pragma unroll
  for (int f = 0; f < 8; ++f) {
    f32x4 s = acc[f];
    f32x4 q = acc[f] * acc[f];
#pragma unroll
    for (int r = 0; r < 4; ++r) {
      s[r] += __shfl_xor(s[r], 1, 64);
      q[r] += __shfl_xor(q[r], 1, 64);
      s[r] += __shfl_xor(s[r], 2, 64);
      q[r] += __shfl_xor(q[r], 2, 64);
    }
    if ((l15 & 3) == 0) {
      *(f32x4*)&sS[wid * 4 + (l15 >> 2)][f * 16 + lq * 4] = s;
      *(f32x4*)&sQ[wid * 4 + (l15 >> 2)][f * 16 + lq * 4] = q;
    }
  }
  __syncthreads();
  if (tid < HID) {
    float s = 0.f, q = 0.f;
#pragma unroll
    for (int r = 0; r < 16; ++r) { s += sS[r][tid]; q += sQ[r][tid]; }
    pS[(size_t)blockIdx.x * HID + tid] = s;
    pQ[(size_t)blockIdx.x * HID + tid] = q;
  }
}

// ---------------- gemm2: W2->LDS, finalize-in-head, Z(packed) + row norms ----------
__global__ __launch_bounds__(256) void k_gemm2(
    const unsigned short* __restrict__ H, const float* __restrict__ W2,
    const float* __restrict__ pS, const float* __restrict__ pQ,
    const float* __restrict__ gamma, const float* __restrict__ beta,
    unsigned short* __restrict__ Z, float* __restrict__ nrm,
    int nb1, int nblk, float n1c, float n2c) {
  __shared__ unsigned short W2L[16384];   // 32KB packed W2
  __shared__ float aux2[64 * 65];         // union: T staging | t0/t1
  __shared__ float s_sc[HID], s_sh[HID];
  const int tid = threadIdx.x, wid = tid >> 6, lane = tid & 63;
  const int l15 = lane & 15, lq = lane >> 4, lk8 = lq * 8;
  const bool set1 = (int)blockIdx.x < nb1;
  // --- BN finalize (uses aux2 as t0/t1) ---
  {
    float* t0 = aux2;
    float* t1 = aux2 + 2 * HID;
    const int col = tid & 127, half = tid >> 7;
    const int b0 = set1 ? 0 : nb1;
    const int nb = set1 ? nb1 : (nblk - nb1);
    float s = 0.f, q = 0.f;
#pragma unroll 4
    for (int b = half; b < nb; b += 2) {
      s += pS[(size_t)(b0 + b) * HID + col];
      q += pQ[(size_t)(b0 + b) * HID + col];
    }
    t0[half * HID + col] = s;
    t1[half * HID + col] = q;
    __syncthreads();
    if (tid < HID) {
      const float ss = t0[tid] + t0[HID + tid];
      const float qq = t1[tid] + t1[HID + tid];
      const float n = set1 ? n1c : n2c;
      const float mean = ss / n;
      const float var = qq / n - mean * mean;
      const float rstd = rsqrtf(var + EPSV);
      const float scale = gamma[tid] * rstd;
      s_sc[tid] = scale;
      s_sh[tid] = beta[tid] - mean * scale;
    }
    __syncthreads();
  }
  // --- W2 (128x128 f32, L2-hot) -> packed LDS ---
  {
    float(*T)[65] = (float(*)[65])aux2;
#pragma unroll 1
    for (int bi = 0; bi < 4; ++bi)
      conv_tile<4>(W2, (bi >> 1) * 64, (bi & 1) * 64, T, W2L, tid);
  }
  // --- GEMM2 body ---
  const int row0 = (int)blockIdx.x * 64 + wid * 16;
  const int strip = row0 >> 4;
  const unsigned short* hptr = H + (size_t)strip * 2048 + (size_t)l15 * 32 + lk8;
  const char* wl = (const char*)W2L + lq * 256 + l15 * 16;
  f32x4 acc[8];
#pragma unroll
  for (int f = 0; f < 8; ++f) acc[f] = (f32x4){0.f, 0.f, 0.f, 0.f};
#pragma unroll
  for (int s = 0; s < 4; ++s) {
    const int k = s * 32 + lk8;
    const bf16x8 hv = *(const bf16x8*)(hptr + (size_t)s * 512);
    const float4 c0 = *(const float4*)&s_sc[k];
    const float4 c1 = *(const float4*)&s_sc[k + 4];
    const float4 d0 = *(const float4*)&s_sh[k];
    const float4 d1 = *(const float4*)&s_sh[k + 4];
    const float cc[8] = {c0.x, c0.y, c0.z, c0.w, c1.x, c1.y, c1.z, c1.w};
    const float dd[8] = {d0.x, d0.y, d0.z, d0.w, d1.x, d1.y, d1.z, d1.w};
    bf16x8 bfr;
#pragma unroll
    for (int i = 0; i < 8; ++i) {
      const float a = fmaxf(fmaf(bf2f((unsigned short)hv[i]), cc[i], dd[i]), 0.f);
      bfr[i] = (short)f2bf(a);
    }
#pragma unroll
    for (int f = 0; f < 8; ++f) {
      const bf16x8 afr = *(const bf16x8*)(wl + (size_t)(f * 4 + s) * 1024);
      acc[f] = __builtin_amdgcn_mfma_f32_16x16x32_bf16(afr, bfr, acc[f], 0, 0, 0);
    }
  }
  float rn = 0.f;
#pragma unroll
  for (int f = 0; f < 8; ++f) {
    rn += acc[f][0] * acc[f][0] + acc[f][1] * acc[f][1] +
          acc[f][2] * acc[f][2] + acc[f][3] * acc[f][3];
    ushort4 z4 = {f2bf(acc[f][0]), f2bf(acc[f][1]), f2bf(acc[f][2]), f2bf(acc[f][3])};
    *(ushort4*)(Z + pack4_off(strip, f, l15, lq)) = z4;
  }
  rn += __shfl_xor(rn, 16, 64);
  rn += __shfl_xor(rn, 32, 64);
  if (lane < 16) nrm[row0 + l15] = rn;
}

// ---------------- dist: packed Z loads, float4 stores, XCD swizzle ----------------
__global__ __launch_bounds__(256) void k_dist(const unsigned short* __restrict__ Z1b,
                                              const unsigned short* __restrict__ Z2b,
                                              const float* __restrict__ n1,
                                              const float* __restrict__ n2,
                                              float* __restrict__ D, int NY, int ntx) {
  const int nwg = (int)gridDim.x;
  const int cpx = nwg >> 3;
  const int bid = (int)blockIdx.x;
  const int wgid = (bid & 7) * cpx + (bid >> 3);
  const int tby = wgid / ntx, tbx = wgid - tby * ntx;

  const int tid = threadIdx.x;
  const int wid = tid >> 6, lane = tid & 63;
  const int wr = wid >> 1, wc = wid & 1;
  const int rowB = tby * 128 + wr * 64;
  const int colB = tbx * 128 + wc * 64;
  const int l15 = lane & 15, lq = lane >> 4;
  const unsigned short* Ap = Z1b + (size_t)(rowB >> 4) * 2048 + (size_t)l15 * 32 + lq * 8;
  const unsigned short* Bp = Z2b + (size_t)(colB >> 4) * 2048 + (size_t)l15 * 32 + lq * 8;
  f32x4 acc[4][4];
#pragma unroll
  for (int i = 0; i < 4; ++i)
#pragma unroll
    for (int j = 0; j < 4; ++j) acc[i][j] = (f32x4){0.f, 0.f, 0.f, 0.f};
#pragma unroll
  for (int s = 0; s < 4; ++s) {
    bf16x8 a[4], b[4];
#pragma unroll
    for (int i = 0; i < 4; ++i) a[i] = *(const bf16x8*)(Ap + (size_t)i * 2048 + (size_t)s * 512);
#pragma unroll
    for (int j = 0; j < 4; ++j) b[j] = *(const bf16x8*)(Bp + (size_t)j * 2048 + (size_t)s * 512);
#pragma unroll
    for (int i = 0; i < 4; ++i)
#pragma unroll
      for (int j = 0; j < 4; ++j)
        acc[i][j] = __builtin_amdgcn_mfma_f32_16x16x32_bf16(b[j], a[i], acc[i][j], 0, 0, 0);
  }
  const int cq = lq * 4;
  float na[4];
#pragma unroll
  for (int i = 0; i < 4; ++i) na[i] = n1[rowB + i * 16 + l15];
#pragma unroll
  for (int j = 0; j < 4; ++j) {
    const float4 nbv = *(const float4*)(n2 + colB + j * 16 + cq);
#pragma unroll
    for (int i = 0; i < 4; ++i) {
      float4 o;
      o.x = na[i] + nbv.x - 2.f * acc[i][j][0];
      o.y = na[i] + nbv.y - 2.f * acc[i][j][1];
      o.z = na[i] + nbv.z - 2.f * acc[i][j][2];
      o.w = na[i] + nbv.w - 2.f * acc[i][j][3];
      *(float4*)(D + (size_t)(rowB + i * 16 + l15) * NY + colB + j * 16 + cq) = o;
    }
  }
}

extern "C" void kernel_launch(void* const* d_in, const int* in_sizes, int n_in,
                              void* d_out, int out_size, void* d_ws, size_t ws_size,
                              hipStream_t stream) {
  const float* variations = (const float*)d_in[0];
  const float* exemplar   = (const float*)d_in[1];
  const float* w1         = (const float*)d_in[2];
  const float* gamma      = (const float*)d_in[3];
  const float* beta       = (const float*)d_in[4];
  const float* w2         = (const float*)d_in[5];
  float* D = (float*)d_out;

  const int nx = in_sizes[0] / LAT;  // 8192
  const int ny = in_sizes[1] / LAT;  // 2048
  const int nrows = nx + ny;         // 10240
  const int nbb = nrows / 64;        // 160
  const int nb1 = nx / 64;           // 128

  char* p = (char*)d_ws;
  unsigned short* Hb = (unsigned short*)p; p += (size_t)nrows * HID * 2;
  unsigned short* Zb = (unsigned short*)p; p += (size_t)nrows * HID * 2;
  float* pS = (float*)p;  p += (size_t)nbb * HID * 4;
  float* pQ = (float*)p;  p += (size_t)nbb * HID * 4;
  float* nrmAll = (float*)p; p += (size_t)nrows * 4;
  float* n1v = nrmAll;
  float* n2v = nrmAll + nx;
  unsigned short* Z1b = Zb;
  unsigned short* Z2b = Zb + (size_t)nx * HID;

  k_gemm1<<<nbb, 256, G1_LDS, stream>>>(variations, exemplar, nx, w1, Hb, pS, pQ);
  k_gemm2<<<nbb, 256, 0, stream>>>(Hb, w2, pS, pQ, gamma, beta, Zb, nrmAll,
                                   nb1, nbb, (float)nx, (float)ny);
  const int ntx = ny / 128;          // 16
  const int nwg = (nx / 128) * ntx;  // 1024
  k_dist<<<nwg, 256, 0, stream>>>(Z1b, Z2b, n1v, n2v, D, ny, ntx);
}